// Round 4
// baseline (612.090 us; speedup 1.0000x reference)
//
#include <hip/hip_runtime.h>

// DIAGNOSTIC ROUND: identical fused kernel as round 3, launched TWICE
// back-to-back (idempotent writes). Purpose: dur_us delta vs round 3
// measures the kernel's true duration, which the top-5 profile masks.
//   T = dur_us(this) - 521us.  T~85-90 => at write roofline. T~180 => pathology.
#define B_DIM 128
#define A_DIM 256
#define E_DIM 256
#define HW    4096   // 64*64
#define CHUNKS_PER_BLOCK 16
#define NBLOCKS (B_DIM * E_DIM / CHUNKS_PER_BLOCK)   // 2048

typedef float f32x4 __attribute__((ext_vector_type(4)));

__global__ void __launch_bounds__(256) fused_embed_kernel(
    const float* __restrict__ action,
    const float* __restrict__ conv_w,
    const float* __restrict__ conv_b,
    f32x4* __restrict__ out)
{
    const int t = threadIdx.x;
    const int ybase = blockIdx.x * CHUNKS_PER_BLOCK;  // 16 consecutive (b,e)
    const int g = t >> 4;          // which chunk this thread's group computes
    const int l = t & 15;          // lane within the 16-thread group
    const int be = ybase + g;
    const int b  = be >> 8;        // E_DIM == 256; all 16 chunks share b
    const int e  = be & 255;

    // Each lane covers 16 consecutive a-elements of the length-256 dot.
    const float4* a4 = reinterpret_cast<const float4*>(action + b * A_DIM + l * 16);
    const float4* w4 = reinterpret_cast<const float4*>(conv_w + e * A_DIM + l * 16);
    float s = 0.0f;
    #pragma unroll
    for (int i = 0; i < 4; ++i) {
        float4 a = a4[i];
        float4 w = w4[i];
        s = fmaf(a.x, w.x, s);
        s = fmaf(a.y, w.y, s);
        s = fmaf(a.z, w.z, s);
        s = fmaf(a.w, w.w, s);
    }
    // Reduce across the 16-lane group (groups are contiguous within a wave64).
    s += __shfl_xor(s, 8, 16);
    s += __shfl_xor(s, 4, 16);
    s += __shfl_xor(s, 2, 16);
    s += __shfl_xor(s, 1, 16);

    __shared__ float ysm[CHUNKS_PER_BLOCK];
    if (l == 0) ysm[g] = fmaxf(s + conv_b[e], 0.0f);
    __syncthreads();

    float yv[CHUNKS_PER_BLOCK];
    #pragma unroll
    for (int k = 0; k < CHUNKS_PER_BLOCK; ++k) yv[k] = ysm[k];

    f32x4* dst = out + (size_t)blockIdx.x * (CHUNKS_PER_BLOCK * HW / 4) + t;
    #pragma unroll
    for (int k = 0; k < CHUNKS_PER_BLOCK; ++k) {
        const f32x4 v4 = {yv[k], yv[k], yv[k], yv[k]};
        #pragma unroll
        for (int j = 0; j < 4; ++j) {
            dst[k * (HW / 4) + j * 256] = v4;
        }
    }
}

extern "C" void kernel_launch(void* const* d_in, const int* in_sizes, int n_in,
                              void* d_out, int out_size, void* d_ws, size_t ws_size,
                              hipStream_t stream) {
    const float* action = (const float*)d_in[0];
    const float* conv_w = (const float*)d_in[1];
    const float* conv_b = (const float*)d_in[2];

    // Launch TWICE: second run writes identical values. dur_us delta vs
    // round 3 == one kernel's duration.
    fused_embed_kernel<<<NBLOCKS, 256, 0, stream>>>(
        action, conv_w, conv_b, reinterpret_cast<f32x4*>(d_out));
    fused_embed_kernel<<<NBLOCKS, 256, 0, stream>>>(
        action, conv_w, conv_b, reinterpret_cast<f32x4*>(d_out));
}